// Round 1
// baseline (1474.437 us; speedup 1.0000x reference)
//
#include <hip/hip_runtime.h>

#define NP 400000
#define KC 64
#define DD 64
#define EPSF 1e-10f
#define LOGN 12.8992195f        // log(400000)
#define LOG1EM30 -69.0775528f   // log(1e-30)
#define CHUNKS (NP / 64)        // 6250

// workspace layout (float indices)
#define W_CENTERS 0
#define W_ACC     4096
#define W_CSQ     8192
#define W_TPA     8256
#define W_TPB     8320
#define W_BL      8384
#define W_OK      8448
#define W_SEXP    8512
#define W_TM      8576
#define W_TV      8640
#define W_DBL     8704          // 8-byte aligned (8704*4 = 34816); dS[0..63]=S0, [64..127]=S1, [128..191]=S2

__global__ __launch_bounds__(256) void prep_kernel(
    const float* __restrict__ centers0, float* __restrict__ ws,
    float* __restrict__ out, int it) {
  float* centers = ws + W_CENTERS;
  float* acc  = ws + W_ACC;
  float* csq  = ws + W_CSQ;
  float* tpA  = ws + W_TPA;
  float* tpB  = ws + W_TPB;
  float* bl   = ws + W_BL;
  float* okf  = ws + W_OK;
  float* Sexp = ws + W_SEXP;
  float* tm   = ws + W_TM;
  float* tv   = ws + W_TV;
  double* dS  = (double*)(ws + W_DBL);
  const int tid = threadIdx.x;
  __shared__ float stm[KC];
  __shared__ int srank[KC];

  if (it == 0) {
    for (int e = tid; e < KC * DD; e += 256) {
      centers[e] = centers0[e];
      acc[e] = 0.f;
    }
    __syncthreads();
    if (tid < KC) {
      float s = 0.f;
      for (int d = 0; d < DD; ++d) { float c = centers[tid * DD + d]; s = fmaf(c, c, s); }
      csq[tid] = s;
      tpA[tid] = 0.f; tpB[tid] = 0.f; bl[tid] = LOGN; okf[tid] = 0.f;
      Sexp[tid] = 1.f;                     // log(1)=0 -> pC = LOGN -> tp = log N (uniform)
      dS[tid] = 0.0; dS[64 + tid] = 0.0; dS[128 + tid] = 0.0;
    }
    return;
  }

  // it >= 1 : finalize previous iteration from the sums
  if (tid < KC) {
    double w  = dS[tid];
    double s1 = dS[64 + tid];
    double s2 = dS[128 + tid];
    double md = s1 / (w + 1e-10);
    double vd = (s2 - 2.0 * md * s1 + md * md * w) / (w + 1e-10);
    tm[tid] = (float)md;
    tv[tid] = (float)vd;
  }
  __syncthreads();
  for (int e = tid; e < KC * DD; e += 256) {
    int k = e >> 6;
    centers[e] = acc[e] / ((float)dS[k] + EPSF);
    acc[e] = 0.f;
  }
  __syncthreads();
  if (tid < KC) {
    float m = tm[tid], var = tv[tid];
    float sigma = sqrtf(fmaxf(var, 0.f));
    bool valid = (sigma > 1e-4f) && (m > 0.f);
    float mu = valid ? m : 0.5f;
    float vv = valid ? var : 1.f;
    float a = (1.f - mu) * mu * mu / vv - mu;
    float b = a / mu - a;
    bool ok = valid && (a > 0.f) && (b > 0.f);
    if (ok) {
      bl[tid]  = lgammaf(a) + lgammaf(b) - lgammaf(a + b);
      tpA[tid] = a - 1.f;
      tpB[tid] = b - 1.f;
      okf[tid] = 1.f;
      Sexp[tid] = 0.f;
    } else {
      bl[tid] = LOGN; tpA[tid] = 0.f; tpB[tid] = 0.f; okf[tid] = 0.f;
      Sexp[tid] = 1.f;
    }
    float s = 0.f;
    for (int d = 0; d < DD; ++d) { float c = centers[tid * DD + d]; s = fmaf(c, c, s); }
    csq[tid] = s;
    dS[tid] = 0.0; dS[64 + tid] = 0.0; dS[128 + tid] = 0.0;
  }

  if (it == 5) {  // final: stable argsort by time_means, write output
    __syncthreads();
    if (tid < KC) stm[tid] = tm[tid];
    __syncthreads();
    if (tid < KC) {
      float mk = stm[tid];
      int r = 0;
      for (int j = 0; j < KC; ++j) {
        float mj = stm[j];
        if (mj < mk || (mj == mk && j < tid)) ++r;
      }
      srank[tid] = r;
    }
    __syncthreads();
    for (int e = tid; e < KC * DD; e += 256) {
      int k = e >> 6;
      out[srank[k] * DD + (e & 63)] = centers[e];
    }
  }
}

// per-k normalizer of the beta pdf over the t grid: Sexp[k] = sum_n exp(log_pdf[n,k])
__global__ __launch_bounds__(256) void expsum_kernel(float* __restrict__ ws) {
  const float* tpA = ws + W_TPA;
  const float* tpB = ws + W_TPB;
  const float* bl  = ws + W_BL;
  const float* okf = ws + W_OK;
  float* Sexp = ws + W_SEXP;
  const int lane = threadIdx.x & 63;
  const int wid = blockIdx.x * 4 + (threadIdx.x >> 6);
  const int nw = gridDim.x * 4;
  const float A = tpA[lane], B = tpB[lane], C = bl[lane];
  const bool ok = okf[lane] > 0.5f;
  float acc = 0.f;
  for (int n = wid; n < NP; n += nw) {
    float t = ((float)n + 0.5f) / (float)NP;
    float lt = logf(t);
    float l1 = log1pf(-t);
    acc += __expf(fmaf(A, lt, fmaf(B, l1, -C)));
  }
  if (ok) atomicAdd(&Sexp[lane], acc);
}

// fused: scores -> softmax -> accumulate W^T X, sum w, sum w t, sum w t^2
__global__ __launch_bounds__(256, 3) void main_kernel(
    const float* __restrict__ x, float* __restrict__ ws) {
  const float* centers = ws + W_CENTERS;
  float* accg = ws + W_ACC;
  const float* csq  = ws + W_CSQ;
  const float* tpA  = ws + W_TPA;
  const float* tpB  = ws + W_TPB;
  const float* bl   = ws + W_BL;
  const float* Sexp = ws + W_SEXP;
  double* dS = (double*)(ws + W_DBL);

  __shared__ __align__(16) float xl[64][68];
  __shared__ __align__(16) float cl[64][68];
  __shared__ __align__(16) float wl[64][68];
  __shared__ float pA[KC], pB[KC], pC[KC], pq[KC];

  const int tid = threadIdx.x;
  for (int e = tid; e < KC * DD; e += 256) cl[e >> 6][e & 63] = centers[e];
  if (tid < KC) {
    pA[tid] = tpA[tid];
    pB[tid] = tpB[tid];
    pC[tid] = bl[tid] + logf(fmaxf(Sexp[tid], EPSF));
    pq[tid] = csq[tid];
  }
  const int kg = tid & 15;   // k-group (phase 1: ks = kg+16j; phase 3: ks = 4kg+i)
  const int pg = tid >> 4;   // phase-1 point group / phase-3 d group
  const int lane = tid & 63;
  const int wh = tid >> 6;
  float acc[4][4] = {};
  double ts0 = 0.0, ts1 = 0.0, ts2 = 0.0;
  __syncthreads();

  for (int ch = blockIdx.x; ch < CHUNKS; ch += gridDim.x) {
    const int n0 = ch * 64;
    const float4* xg = (const float4*)(x + (size_t)n0 * DD);
    for (int f = tid; f < 1024; f += 256) {
      float4 v = xg[f];
      *(float4*)&xl[f >> 4][(f & 15) << 2] = v;
    }
    __syncthreads();

    // phase 1: s[i][j] = dot(x_{4pg+i}, c_{kg+16j})
    float s[4][4] = {};
    #pragma unroll 4
    for (int d4 = 0; d4 < DD; d4 += 4) {
      float4 xv[4], cv[4];
      #pragma unroll
      for (int i = 0; i < 4; ++i) xv[i] = *(const float4*)&xl[pg * 4 + i][d4];
      #pragma unroll
      for (int j = 0; j < 4; ++j) cv[j] = *(const float4*)&cl[kg + 16 * j][d4];
      #pragma unroll
      for (int i = 0; i < 4; ++i) {
        #pragma unroll
        for (int j = 0; j < 4; ++j) {
          s[i][j] = fmaf(xv[i].x, cv[j].x, s[i][j]);
          s[i][j] = fmaf(xv[i].y, cv[j].y, s[i][j]);
          s[i][j] = fmaf(xv[i].z, cv[j].z, s[i][j]);
          s[i][j] = fmaf(xv[i].w, cv[j].w, s[i][j]);
        }
      }
    }
    // epilogue: score = 2*dot - csq - time_prior  (time prior in log space, clipped)
    #pragma unroll
    for (int i = 0; i < 4; ++i) {
      const int p = pg * 4 + i;
      float t  = ((float)(n0 + p) + 0.5f) / (float)NP;
      float lt = logf(t);
      float l1 = log1pf(-t);
      #pragma unroll
      for (int j = 0; j < 4; ++j) {
        const int k = kg + 16 * j;
        float logy = fmaf(pA[k], lt, fmaf(pB[k], l1, -pC[k]));
        logy = fminf(fmaxf(logy, LOG1EM30), 0.f);
        wl[p][k] = fmaf(2.f, s[i][j], -pq[k]) + logy;   // + logy == - tp
      }
    }
    __syncthreads();

    // phase 2: row softmax (4 threads per point, shuffle-combine)
    {
      const int p = tid >> 2, q = tid & 3;
      float4 sv[4];
      #pragma unroll
      for (int i = 0; i < 4; ++i) sv[i] = *(const float4*)&wl[p][q * 16 + i * 4];
      float m = -3e38f;
      #pragma unroll
      for (int i = 0; i < 4; ++i)
        m = fmaxf(m, fmaxf(fmaxf(sv[i].x, sv[i].y), fmaxf(sv[i].z, sv[i].w)));
      m = fmaxf(m, __shfl_xor(m, 1));
      m = fmaxf(m, __shfl_xor(m, 2));
      float l = 0.f;
      #pragma unroll
      for (int i = 0; i < 4; ++i) {
        sv[i].x = __expf(sv[i].x - m); sv[i].y = __expf(sv[i].y - m);
        sv[i].z = __expf(sv[i].z - m); sv[i].w = __expf(sv[i].w - m);
        l += (sv[i].x + sv[i].y) + (sv[i].z + sv[i].w);
      }
      l += __shfl_xor(l, 1);
      l += __shfl_xor(l, 2);
      const float inv = 1.f / l;
      #pragma unroll
      for (int i = 0; i < 4; ++i) {
        sv[i].x *= inv; sv[i].y *= inv; sv[i].z *= inv; sv[i].w *= inv;
        *(float4*)&wl[p][q * 16 + i * 4] = sv[i];
      }
    }
    __syncthreads();

    // phase 3a: time statistics (lane = k), fp32 chunk partials -> fp64 running
    {
      float c0 = 0.f, c1 = 0.f, c2 = 0.f;
      #pragma unroll 4
      for (int pp = 0; pp < 16; ++pp) {
        const int p = wh * 16 + pp;
        const float w = wl[p][lane];
        const float t = ((float)(n0 + p) + 0.5f) / (float)NP;
        c0 += w;
        c1 = fmaf(w, t, c1);
        c2 = fmaf(w, t * t, c2);
      }
      ts0 += (double)c0; ts1 += (double)c1; ts2 += (double)c2;
    }
    // phase 3b: acc += W^T X  (thread tile: ks = 4kg+i, ds = 4pg+j)
    #pragma unroll 4
    for (int p = 0; p < 64; ++p) {
      const float4 wv = *(const float4*)&wl[p][kg * 4];
      const float4 xv = *(const float4*)&xl[p][pg * 4];
      const float wa[4] = {wv.x, wv.y, wv.z, wv.w};
      const float xa[4] = {xv.x, xv.y, xv.z, xv.w};
      #pragma unroll
      for (int i = 0; i < 4; ++i)
        #pragma unroll
        for (int j = 0; j < 4; ++j)
          acc[i][j] = fmaf(wa[i], xa[j], acc[i][j]);
    }
    __syncthreads();
  }

  // flush center numerators
  #pragma unroll
  for (int i = 0; i < 4; ++i)
    #pragma unroll
    for (int j = 0; j < 4; ++j)
      atomicAdd(&accg[(kg * 4 + i) * DD + pg * 4 + j], acc[i][j]);

  // reduce time stats across the block (reuse wl as double scratch), then fp64 atomics
  double* dred = (double*)&wl[0][0];
  dred[wh * 64 + lane] = ts0;
  dred[256 + wh * 64 + lane] = ts1;
  dred[512 + wh * 64 + lane] = ts2;
  __syncthreads();
  if (tid < 64) {
    double a0 = (dred[tid] + dred[64 + tid]) + (dred[128 + tid] + dred[192 + tid]);
    double a1 = (dred[256 + tid] + dred[320 + tid]) + (dred[384 + tid] + dred[448 + tid]);
    double a2 = (dred[512 + tid] + dred[576 + tid]) + (dred[640 + tid] + dred[704 + tid]);
    atomicAdd(&dS[tid], a0);
    atomicAdd(&dS[64 + tid], a1);
    atomicAdd(&dS[128 + tid], a2);
  }
}

extern "C" void kernel_launch(void* const* d_in, const int* in_sizes, int n_in,
                              void* d_out, int out_size, void* d_ws, size_t ws_size,
                              hipStream_t stream) {
  const float* x  = (const float*)d_in[0];
  const float* c0 = (const float*)d_in[1];
  float* out = (float*)d_out;
  float* ws  = (float*)d_ws;   // uses ~37 KB

  for (int it = 0; it < 5; ++it) {
    hipLaunchKernelGGL(prep_kernel, dim3(1), dim3(256), 0, stream, c0, ws, out, it);
    if (it > 0)
      hipLaunchKernelGGL(expsum_kernel, dim3(512), dim3(256), 0, stream, ws);
    hipLaunchKernelGGL(main_kernel, dim3(768), dim3(256), 0, stream, x, ws);
  }
  hipLaunchKernelGGL(prep_kernel, dim3(1), dim3(256), 0, stream, c0, ws, out, 5);
}

// Round 2
// 958.266 us; speedup vs baseline: 1.5387x; 1.5387x over previous
//
#include <hip/hip_runtime.h>

#define NP 400000
#define KC 64
#define DD 64
#define CHUNKS (NP / 64)     // 6250
#define EPSF 1e-10f
#define LOGN 12.8992195f     // log(400000)
#define NSLOT 8

// workspace float-index layout
#define W_CENTERS 0          // 4096
#define W_CSQ   4096         // 64
#define W_TPA   4160
#define W_TPB   4224
#define W_BL    4288
#define W_SEXP  4352
#define W_TM    4416
#define W_TV    4480
#define W_OK    4544
#define W_ACC8  4608         // NSLOT*4096 = 32768 floats
#define W_DS8   37376        // byte off 149504 (8B aligned); NSLOT*192 doubles

typedef __bf16 bf16;
typedef bf16 bf16x4 __attribute__((ext_vector_type(4)));
typedef bf16 bf16x8 __attribute__((ext_vector_type(8)));
typedef float f32x4 __attribute__((ext_vector_type(4)));

__device__ __forceinline__ f32x4 mfma16(bf16x8 a, bf16x8 b, f32x4 c) {
  return __builtin_amdgcn_mfma_f32_16x16x32_bf16(a, b, c, 0, 0, 0);
}

// ---------------------------------------------------------------- prep
__global__ __launch_bounds__(256) void prep_kernel(
    const float* __restrict__ centers0, float* __restrict__ ws,
    float* __restrict__ out, int it) {
  float* centers = ws + W_CENTERS;
  float* csq  = ws + W_CSQ;
  float* tpA  = ws + W_TPA;
  float* tpB  = ws + W_TPB;
  float* bl   = ws + W_BL;
  float* Sexp = ws + W_SEXP;
  float* tm   = ws + W_TM;
  float* tv   = ws + W_TV;
  float* okf  = ws + W_OK;
  float* acc8 = ws + W_ACC8;
  double* dS8 = (double*)(ws + W_DS8);
  const int tid = threadIdx.x;
  __shared__ float sw[64];
  __shared__ float stm[64];
  __shared__ int srank[64];

  if (it == 0) {
    for (int e = tid; e < 4096; e += 256) centers[e] = centers0[e];
    for (int e = tid; e < NSLOT * 4096; e += 256) acc8[e] = 0.f;
    for (int e = tid; e < NSLOT * 192; e += 256) dS8[e] = 0.0;
    __syncthreads();
    if (tid < 64) {
      float s = 0.f;
      for (int d = 0; d < 64; ++d) { float c = centers[tid * 64 + d]; s = fmaf(c, c, s); }
      csq[tid] = s;
      tpA[tid] = 0.f; tpB[tid] = 0.f; bl[tid] = LOGN; Sexp[tid] = 1.f; okf[tid] = 0.f;
    }
    return;
  }

  // finalize previous iteration: reduce slots
  if (tid < 64) {
    double w = 0.0, s1 = 0.0, s2 = 0.0;
    for (int s = 0; s < NSLOT; ++s) {
      w  += dS8[s * 192 + tid];
      s1 += dS8[s * 192 + 64 + tid];
      s2 += dS8[s * 192 + 128 + tid];
    }
    double md = s1 / (w + 1e-10);
    double vd = (s2 - 2.0 * md * s1 + md * md * w) / (w + 1e-10);
    tm[tid] = (float)md;
    tv[tid] = (float)vd;
    sw[tid] = (float)w;
  }
  __syncthreads();
  for (int e4 = tid; e4 < 1024; e4 += 256) {
    f32x4 s = {0.f, 0.f, 0.f, 0.f};
    #pragma unroll
    for (int slot = 0; slot < NSLOT; ++slot)
      s += *(const f32x4*)&acc8[slot * 4096 + e4 * 4];
    float dv = sw[e4 >> 4] + EPSF;
    s.x /= dv; s.y /= dv; s.z /= dv; s.w /= dv;
    *(f32x4*)&centers[e4 * 4] = s;
  }
  __syncthreads();
  for (int e = tid; e < NSLOT * 4096; e += 256) acc8[e] = 0.f;
  for (int e = tid; e < NSLOT * 192; e += 256) dS8[e] = 0.0;
  if (tid < 64) {
    float m = tm[tid], var = tv[tid];
    float sigma = sqrtf(fmaxf(var, 0.f));
    bool valid = (sigma > 1e-4f) && (m > 0.f);
    float mu = valid ? m : 0.5f;
    float vvv = valid ? var : 1.f;
    float a = (1.f - mu) * mu * mu / vvv - mu;
    float b = a / mu - a;
    bool ok = valid && (a > 0.f) && (b > 0.f);
    if (ok) {
      bl[tid]  = lgammaf(a) + lgammaf(b) - lgammaf(a + b);
      tpA[tid] = a - 1.f;
      tpB[tid] = b - 1.f;
      okf[tid] = 1.f;
      Sexp[tid] = 0.f;
    } else {
      bl[tid] = LOGN; tpA[tid] = 0.f; tpB[tid] = 0.f; okf[tid] = 0.f; Sexp[tid] = 1.f;
    }
    float s = 0.f;
    for (int d = 0; d < 64; ++d) { float c = centers[tid * 64 + d]; s = fmaf(c, c, s); }
    csq[tid] = s;
  }

  if (it == 5) {  // final: stable argsort by time_means, write output
    __syncthreads();
    if (tid < 64) stm[tid] = tm[tid];
    __syncthreads();
    if (tid < 64) {
      float mk = stm[tid];
      int r = 0;
      for (int j = 0; j < 64; ++j) {
        float mj = stm[j];
        if (mj < mk || (mj == mk && j < tid)) ++r;
      }
      srank[tid] = r;
    }
    __syncthreads();
    for (int e = tid; e < 4096; e += 256)
      out[srank[e >> 6] * 64 + (e & 63)] = centers[e];
  }
}

// ------------------------------------------------------------- expsum
__global__ __launch_bounds__(256) void expsum_kernel(float* __restrict__ ws) {
  const float* tpA = ws + W_TPA;
  const float* tpB = ws + W_TPB;
  const float* bl  = ws + W_BL;
  const float* okf = ws + W_OK;
  float* Sexp = ws + W_SEXP;
  const int lane = threadIdx.x & 63;
  const int wid = blockIdx.x * 4 + (threadIdx.x >> 6);
  const int nw = gridDim.x * 4;
  const float A = tpA[lane], B = tpB[lane], C = bl[lane];
  const bool ok = okf[lane] > 0.5f;
  float acc = 0.f;
  for (int n = wid; n < NP; n += nw) {
    float t = ((float)n + 0.5f) / (float)NP;
    float lt = logf(t);
    float l1 = log1pf(-t);
    acc += __expf(fmaf(A, lt, fmaf(B, l1, -C)));
  }
  if (ok) unsafeAtomicAdd(&Sexp[lane], acc);
}

// ---------------------------------------------------------------- main
// Fused MFMA iteration: scores (S^T = C.X^T via bf16-split) -> in-register
// softmax -> W^T.X via bf16-split MFMA + fp64 time stats.
__global__ __launch_bounds__(256, 2) void main_kernel(
    const float* __restrict__ x, float* __restrict__ ws) {
  const float* centers = ws + W_CENTERS;
  const float* csq  = ws + W_CSQ;
  const float* tpA  = ws + W_TPA;
  const float* tpB  = ws + W_TPB;
  const float* bl   = ws + W_BL;
  const float* Sexp = ws + W_SEXP;
  float* acc8 = ws + W_ACC8;
  double* dS8 = (double*)(ws + W_DS8);

  __shared__ __align__(16) unsigned char smem[49152];
  bf16* xl_h = (bf16*)smem;              // [p][d] row-major, swizzled
  bf16* xl_l = (bf16*)(smem + 8192);
  bf16* xt_h = (bf16*)(smem + 16384);    // [d][p] transposed, swizzled
  bf16* xt_l = (bf16*)(smem + 24576);
  bf16* wt_h = (bf16*)(smem + 32768);    // [c][p] transposed W, swizzled
  bf16* wt_l = (bf16*)(smem + 40960);

  const int tid  = threadIdx.x;
  const int wv   = tid >> 6;
  const int lane = tid & 63;
  const int ln   = lane & 15;
  const int h    = lane >> 4;

  // per-lane time-prior params for the 16 c-rows this lane owns in S^T frags
  float pA_[4][4], pB_[4][4], pC_[4][4], ph_[4][4];
  #pragma unroll
  for (int mc = 0; mc < 4; ++mc)
    #pragma unroll
    for (int r = 0; r < 4; ++r) {
      int c = 16 * mc + 4 * h + r;
      pA_[mc][r] = tpA[c];
      pB_[mc][r] = tpB[c];
      pC_[mc][r] = bl[c] + logf(fmaxf(Sexp[c], EPSF));
      ph_[mc][r] = -0.5f * csq[c];
    }

  // preload C fragments (A-operand of phase 1), hi/lo bf16 split
  bf16x8 cah[4][2], cal[4][2];
  #pragma unroll
  for (int mc = 0; mc < 4; ++mc)
    #pragma unroll
    for (int ks = 0; ks < 2; ++ks) {
      const float* cp = centers + (16 * mc + ln) * 64 + 32 * ks + 8 * h;
      #pragma unroll
      for (int j = 0; j < 8; ++j) {
        float v = cp[j];
        bf16 hh = (bf16)v;
        cah[mc][ks][j] = hh;
        cal[mc][ks][j] = (bf16)(v - (float)hh);
      }
    }

  f32x4 pacc[4];
  #pragma unroll
  for (int tn = 0; tn < 4; ++tn) { pacc[tn].x = 0.f; pacc[tn].y = 0.f; pacc[tn].z = 0.f; pacc[tn].w = 0.f; }
  double ts0 = 0.0, ts1 = 0.0, ts2 = 0.0;

  const int stride = gridDim.x;
  int ch = blockIdx.x;
  f32x4 rv[4];
  {
    const f32x4* xg = (const f32x4*)(x + (size_t)ch * 4096);
    #pragma unroll
    for (int i = 0; i < 4; ++i) rv[i] = xg[tid + 256 * i];
  }

  for (; ch < CHUNKS; ch += stride) {
    const int n0 = ch * 64;
    f32x4 rv2[4];
    const bool hasnext = (ch + stride) < CHUNKS;
    if (hasnext) {
      const f32x4* xg = (const f32x4*)(x + (size_t)(ch + stride) * 4096);
      #pragma unroll
      for (int i = 0; i < 4; ++i) rv2[i] = xg[tid + 256 * i];
    }

    // convert current chunk -> xl (row-major, swizzled)
    #pragma unroll
    for (int i = 0; i < 4; ++i) {
      int p  = (tid >> 4) + 16 * i;
      int d0 = (tid & 15) * 4;
      f32x4 v = rv[i];
      bf16x4 hh, ll;
      #pragma unroll
      for (int j = 0; j < 4; ++j) {
        float vj = (j == 0) ? v.x : (j == 1) ? v.y : (j == 2) ? v.z : v.w;
        bf16 b = (bf16)vj;
        hh[j] = b;
        ll[j] = (bf16)(vj - (float)b);
      }
      int e = p * 64 + (d0 ^ ((p & 7) << 3));
      *(bf16x4*)&xl_h[e] = hh;
      *(bf16x4*)&xl_l[e] = ll;
    }
    __syncthreads();

    // phase 1: S^T[c][p] = C . X^T  (3-term bf16 split), wave wv owns p-slab
    f32x4 facc[4];
    #pragma unroll
    for (int mc = 0; mc < 4; ++mc) {
      facc[mc].x = ph_[mc][0]; facc[mc].y = ph_[mc][1];
      facc[mc].z = ph_[mc][2]; facc[mc].w = ph_[mc][3];
    }
    const int prow = 16 * wv + ln;
    #pragma unroll
    for (int ks = 0; ks < 2; ++ks) {
      int e = prow * 64 + ((32 * ks + 8 * h) ^ ((prow & 7) << 3));
      bf16x8 bxh = *(bf16x8*)&xl_h[e];
      bf16x8 bxl = *(bf16x8*)&xl_l[e];
      #pragma unroll
      for (int mc = 0; mc < 4; ++mc) {
        facc[mc] = mfma16(cah[mc][ks], bxh, facc[mc]);
        facc[mc] = mfma16(cah[mc][ks], bxl, facc[mc]);
        facc[mc] = mfma16(cal[mc][ks], bxh, facc[mc]);
      }
    }

    // epilogue + in-register softmax over c (16 per lane + xor16/xor32)
    {
      float t  = ((float)(n0 + prow) + 0.5f) / (float)NP;
      float lt = logf(t);
      float l1 = log1pf(-t);
      float m = -3.0e38f;
      #pragma unroll
      for (int mc = 0; mc < 4; ++mc)
        #pragma unroll
        for (int r = 0; r < 4; ++r) {
          float u = fmaf(pA_[mc][r], lt, fmaf(pB_[mc][r], l1, -pC_[mc][r]));
          u = fminf(fmaxf(u, -69.0775528f), 0.0f);
          float fa = (r == 0) ? facc[mc].x : (r == 1) ? facc[mc].y : (r == 2) ? facc[mc].z : facc[mc].w;
          float val = fmaf(2.0f, fa, u);
          if (r == 0) facc[mc].x = val; else if (r == 1) facc[mc].y = val;
          else if (r == 2) facc[mc].z = val; else facc[mc].w = val;
          m = fmaxf(m, val);
        }
      m = fmaxf(m, __shfl_xor(m, 16));
      m = fmaxf(m, __shfl_xor(m, 32));
      float lsum = 0.f;
      #pragma unroll
      for (int mc = 0; mc < 4; ++mc) {
        facc[mc].x = __expf(facc[mc].x - m); lsum += facc[mc].x;
        facc[mc].y = __expf(facc[mc].y - m); lsum += facc[mc].y;
        facc[mc].z = __expf(facc[mc].z - m); lsum += facc[mc].z;
        facc[mc].w = __expf(facc[mc].w - m); lsum += facc[mc].w;
      }
      lsum += __shfl_xor(lsum, 16);
      lsum += __shfl_xor(lsum, 32);
      float inv = 1.0f / lsum;
      #pragma unroll
      for (int mc = 0; mc < 4; ++mc)
        #pragma unroll
        for (int r = 0; r < 4; ++r) {
          float wval = ((r == 0) ? facc[mc].x : (r == 1) ? facc[mc].y : (r == 2) ? facc[mc].z : facc[mc].w) * inv;
          bf16 bh = (bf16)wval;
          bf16 bl2 = (bf16)(wval - (float)bh);
          int c = 16 * mc + 4 * h + r;
          int e = c * 64 + (prow ^ ((c & 7) << 3));
          wt_h[e] = bh;
          wt_l[e] = bl2;
        }
    }

    // transpose xl -> xt (row-read / row-write, conflict-free)
    #pragma unroll
    for (int s = 0; s < 2; ++s) {
      int d0 = 8 * (2 * wv + s);
      int ep = lane * 64 + (d0 ^ ((lane & 7) << 3));
      bf16x8 vh = *(bf16x8*)&xl_h[ep];
      bf16x8 vl = *(bf16x8*)&xl_l[ep];
      #pragma unroll
      for (int j = 0; j < 8; ++j) {
        int e = (d0 + j) * 64 + (lane ^ (j << 3));
        xt_h[e] = vh[j];
        xt_l[e] = vl[j];
      }
    }
    __syncthreads();

    // phase 3a: time stats (c = lane, p-slab by wave), fp32 chunk -> fp64
    {
      float c0 = 0.f, c1 = 0.f, c2 = 0.f;
      #pragma unroll
      for (int s = 0; s < 2; ++s) {
        int p0 = 16 * wv + 8 * s;
        int e = lane * 64 + (p0 ^ ((lane & 7) << 3));
        bf16x8 vh = *(bf16x8*)&wt_h[e];
        bf16x8 vl = *(bf16x8*)&wt_l[e];
        #pragma unroll
        for (int j = 0; j < 8; ++j) {
          float wval = (float)vh[j] + (float)vl[j];
          float tt = ((float)(n0 + p0 + j) + 0.5f) / (float)NP;
          c0 += wval;
          c1 = fmaf(wval, tt, c1);
          c2 = fmaf(wval, tt * tt, c2);
        }
      }
      ts0 += (double)c0; ts1 += (double)c1; ts2 += (double)c2;
    }

    // phase 3b: ACC[c][d] += W^T . X  (3-term bf16 split)
    {
      const int ca = 16 * wv + ln;
      #pragma unroll
      for (int ks = 0; ks < 2; ++ks) {
        int p0 = 32 * ks + 8 * h;
        int ea = ca * 64 + (p0 ^ ((ca & 7) << 3));
        bf16x8 awh = *(bf16x8*)&wt_h[ea];
        bf16x8 awl = *(bf16x8*)&wt_l[ea];
        #pragma unroll
        for (int tn = 0; tn < 4; ++tn) {
          int d = 16 * tn + ln;
          int e = d * 64 + (p0 ^ ((d & 7) << 3));
          bf16x8 bxh = *(bf16x8*)&xt_h[e];
          bf16x8 bxl = *(bf16x8*)&xt_l[e];
          pacc[tn] = mfma16(awh, bxh, pacc[tn]);
          pacc[tn] = mfma16(awh, bxl, pacc[tn]);
          pacc[tn] = mfma16(awl, bxh, pacc[tn]);
        }
      }
    }
    __syncthreads();
    if (hasnext) {
      #pragma unroll
      for (int i = 0; i < 4; ++i) rv[i] = rv2[i];
    }
  }

  // flush center numerators into slotted accumulators (64 adds/address)
  const int slot = blockIdx.x & (NSLOT - 1);
  #pragma unroll
  for (int tn = 0; tn < 4; ++tn)
    #pragma unroll
    for (int r = 0; r < 4; ++r) {
      float v = (r == 0) ? pacc[tn].x : (r == 1) ? pacc[tn].y : (r == 2) ? pacc[tn].z : pacc[tn].w;
      unsafeAtomicAdd(&acc8[slot * 4096 + (16 * wv + 4 * h + r) * 64 + 16 * tn + ln], v);
    }

  // block-reduce fp64 stats, then slotted fp64 atomics
  double* dred = (double*)smem;
  dred[tid] = ts0; dred[256 + tid] = ts1; dred[512 + tid] = ts2;
  __syncthreads();
  if (tid < 64) {
    double a0 = (dred[tid] + dred[64 + tid]) + (dred[128 + tid] + dred[192 + tid]);
    double a1 = (dred[256 + tid] + dred[320 + tid]) + (dred[384 + tid] + dred[448 + tid]);
    double a2 = (dred[512 + tid] + dred[576 + tid]) + (dred[640 + tid] + dred[704 + tid]);
    unsafeAtomicAdd(&dS8[slot * 192 + tid], a0);
    unsafeAtomicAdd(&dS8[slot * 192 + 64 + tid], a1);
    unsafeAtomicAdd(&dS8[slot * 192 + 128 + tid], a2);
  }
}

// -------------------------------------------------------------- launch
extern "C" void kernel_launch(void* const* d_in, const int* in_sizes, int n_in,
                              void* d_out, int out_size, void* d_ws, size_t ws_size,
                              hipStream_t stream) {
  const float* x  = (const float*)d_in[0];
  const float* c0 = (const float*)d_in[1];
  float* out = (float*)d_out;
  float* ws  = (float*)d_ws;   // uses ~160 KB

  for (int it = 0; it < 5; ++it) {
    hipLaunchKernelGGL(prep_kernel, dim3(1), dim3(256), 0, stream, c0, ws, out, it);
    if (it > 0)
      hipLaunchKernelGGL(expsum_kernel, dim3(512), dim3(256), 0, stream, ws);
    hipLaunchKernelGGL(main_kernel, dim3(512), dim3(256), 0, stream, x, ws);
  }
  hipLaunchKernelGGL(prep_kernel, dim3(1), dim3(256), 0, stream, c0, ws, out, 5);
}

// Round 3
// 928.770 us; speedup vs baseline: 1.5875x; 1.0318x over previous
//
#include <hip/hip_runtime.h>

#define NP 400000
#define KC 64
#define DD 64
#define CHUNKS (NP / 64)     // 6250
#define EPSF 1e-10f
#define LOGN 12.8992195f     // log(400000)
#define NSLOT 8

// workspace float-index layout
#define W_CENTERS 0          // 4096
#define W_CSQ   4096         // 64
#define W_TPA   4160
#define W_TPB   4224
#define W_BL    4288
#define W_SEXP  4352
#define W_TM    4416
#define W_TV    4480
#define W_OK    4544
#define W_ACC8  4608         // NSLOT*4096 = 32768 floats
#define W_DS8   37376        // byte off 149504 (8B aligned); NSLOT*192 doubles
#define W_TAB   40448        // byte off 161792; float2[NP] = 3.2 MB
#define WS_NEEDED ((W_TAB + 2 * NP) * 4)

typedef __bf16 bf16;
typedef bf16 bf16x4 __attribute__((ext_vector_type(4)));
typedef bf16 bf16x8 __attribute__((ext_vector_type(8)));
typedef float f32x4 __attribute__((ext_vector_type(4)));

__device__ __forceinline__ f32x4 mfma16(bf16x8 a, bf16x8 b, f32x4 c) {
  return __builtin_amdgcn_mfma_f32_16x16x32_bf16(a, b, c, 0, 0, 0);
}

// ---------------------------------------------------------------- prep
__global__ __launch_bounds__(256) void prep_kernel(
    const float* __restrict__ centers0, float* __restrict__ ws,
    float* __restrict__ out, int it) {
  float* centers = ws + W_CENTERS;
  float* csq  = ws + W_CSQ;
  float* tpA  = ws + W_TPA;
  float* tpB  = ws + W_TPB;
  float* bl   = ws + W_BL;
  float* Sexp = ws + W_SEXP;
  float* tm   = ws + W_TM;
  float* tv   = ws + W_TV;
  float* okf  = ws + W_OK;
  float* acc8 = ws + W_ACC8;
  double* dS8 = (double*)(ws + W_DS8);
  const int tid = threadIdx.x;
  __shared__ float sw[64];
  __shared__ float stm[64];
  __shared__ int srank[64];

  if (it == 0) {
    for (int e = tid; e < 4096; e += 256) centers[e] = centers0[e];
    for (int e = tid; e < NSLOT * 4096; e += 256) acc8[e] = 0.f;
    for (int e = tid; e < NSLOT * 192; e += 256) dS8[e] = 0.0;
    __syncthreads();
    if (tid < 64) {
      float s = 0.f;
      for (int d = 0; d < 64; ++d) { float c = centers[tid * 64 + d]; s = fmaf(c, c, s); }
      csq[tid] = s;
      tpA[tid] = 0.f; tpB[tid] = 0.f; bl[tid] = LOGN; Sexp[tid] = 1.f; okf[tid] = 0.f;
    }
    return;
  }

  // finalize previous iteration: reduce slots
  if (tid < 64) {
    double w = 0.0, s1 = 0.0, s2 = 0.0;
    for (int s = 0; s < NSLOT; ++s) {
      w  += dS8[s * 192 + tid];
      s1 += dS8[s * 192 + 64 + tid];
      s2 += dS8[s * 192 + 128 + tid];
    }
    double md = s1 / (w + 1e-10);
    double vd = (s2 - 2.0 * md * s1 + md * md * w) / (w + 1e-10);
    tm[tid] = (float)md;
    tv[tid] = (float)vd;
    sw[tid] = (float)w;
  }
  __syncthreads();
  for (int e4 = tid; e4 < 1024; e4 += 256) {
    f32x4 s = {0.f, 0.f, 0.f, 0.f};
    #pragma unroll
    for (int slot = 0; slot < NSLOT; ++slot)
      s += *(const f32x4*)&acc8[slot * 4096 + e4 * 4];
    float dv = sw[e4 >> 4] + EPSF;
    s.x /= dv; s.y /= dv; s.z /= dv; s.w /= dv;
    *(f32x4*)&centers[e4 * 4] = s;
  }
  __syncthreads();
  for (int e = tid; e < NSLOT * 4096; e += 256) acc8[e] = 0.f;
  for (int e = tid; e < NSLOT * 192; e += 256) dS8[e] = 0.0;
  if (tid < 64) {
    float m = tm[tid], var = tv[tid];
    float sigma = sqrtf(fmaxf(var, 0.f));
    bool valid = (sigma > 1e-4f) && (m > 0.f);
    float mu = valid ? m : 0.5f;
    float vvv = valid ? var : 1.f;
    float a = (1.f - mu) * mu * mu / vvv - mu;
    float b = a / mu - a;
    bool ok = valid && (a > 0.f) && (b > 0.f);
    if (ok) {
      bl[tid]  = lgammaf(a) + lgammaf(b) - lgammaf(a + b);
      tpA[tid] = a - 1.f;
      tpB[tid] = b - 1.f;
      okf[tid] = 1.f;
      Sexp[tid] = 0.f;
    } else {
      bl[tid] = LOGN; tpA[tid] = 0.f; tpB[tid] = 0.f; okf[tid] = 0.f; Sexp[tid] = 1.f;
    }
    float s = 0.f;
    for (int d = 0; d < 64; ++d) { float c = centers[tid * 64 + d]; s = fmaf(c, c, s); }
    csq[tid] = s;
  }

  if (it == 5) {  // final: stable argsort by time_means, write output
    __syncthreads();
    if (tid < 64) stm[tid] = tm[tid];
    __syncthreads();
    if (tid < 64) {
      float mk = stm[tid];
      int r = 0;
      for (int j = 0; j < 64; ++j) {
        float mj = stm[j];
        if (mj < mk || (mj == mk && j < tid)) ++r;
      }
      srank[tid] = r;
    }
    __syncthreads();
    for (int e = tid; e < 4096; e += 256)
      out[srank[e >> 6] * 64 + (e & 63)] = centers[e];
  }
}

// --------------------------------------------------- log table (once/call)
__global__ __launch_bounds__(256) void table_kernel(float* __restrict__ ws) {
  float2* tab = (float2*)(ws + W_TAB);
  const int gid = blockIdx.x * 256 + threadIdx.x;
  const int stride = gridDim.x * 256;
  for (int n = gid; n < NP; n += stride) {
    float t = ((float)n + 0.5f) / (float)NP;
    tab[n] = make_float2(logf(t), log1pf(-t));
  }
}

// ------------------------------------------- expsum via precomputed table
__global__ __launch_bounds__(256) void expsum_tab_kernel(float* __restrict__ ws) {
  const float* tpA = ws + W_TPA;
  const float* tpB = ws + W_TPB;
  const float* bl  = ws + W_BL;
  const float* okf = ws + W_OK;
  const float2* tab = (const float2*)(ws + W_TAB);
  float* Sexp = ws + W_SEXP;
  const int lane = threadIdx.x & 63;
  const int wid = blockIdx.x * 4 + (threadIdx.x >> 6);
  const int nw = gridDim.x * 4;
  const float A = tpA[lane], B = tpB[lane], C = bl[lane];
  const bool ok = okf[lane] > 0.5f;
  float acc = 0.f;
  // unrolled-by-4 broadcast loads to pipeline latency
  int n = wid;
  for (; n + 3 * nw < NP; n += 4 * nw) {
    float2 v0 = tab[n];
    float2 v1 = tab[n + nw];
    float2 v2 = tab[n + 2 * nw];
    float2 v3 = tab[n + 3 * nw];
    acc += __expf(fmaf(A, v0.x, fmaf(B, v0.y, -C)));
    acc += __expf(fmaf(A, v1.x, fmaf(B, v1.y, -C)));
    acc += __expf(fmaf(A, v2.x, fmaf(B, v2.y, -C)));
    acc += __expf(fmaf(A, v3.x, fmaf(B, v3.y, -C)));
  }
  for (; n < NP; n += nw) {
    float2 v = tab[n];
    acc += __expf(fmaf(A, v.x, fmaf(B, v.y, -C)));
  }
  if (ok) unsafeAtomicAdd(&Sexp[lane], acc);
}

// ---------------------------- expsum fallback (no table space in ws)
__global__ __launch_bounds__(256) void expsum_kernel(float* __restrict__ ws) {
  const float* tpA = ws + W_TPA;
  const float* tpB = ws + W_TPB;
  const float* bl  = ws + W_BL;
  const float* okf = ws + W_OK;
  float* Sexp = ws + W_SEXP;
  const int lane = threadIdx.x & 63;
  const int wid = blockIdx.x * 4 + (threadIdx.x >> 6);
  const int nw = gridDim.x * 4;
  const float A = tpA[lane], B = tpB[lane], C = bl[lane];
  const bool ok = okf[lane] > 0.5f;
  float acc = 0.f;
  for (int n = wid; n < NP; n += nw) {
    float t = ((float)n + 0.5f) / (float)NP;
    float lt = logf(t);
    float l1 = log1pf(-t);
    acc += __expf(fmaf(A, lt, fmaf(B, l1, -C)));
  }
  if (ok) unsafeAtomicAdd(&Sexp[lane], acc);
}

// ---------------------------------------------------------------- main
// Fused MFMA iteration: scores (S^T = C.X^T via bf16-split) -> in-register
// softmax -> W^T.X via bf16-split MFMA + fp64 time stats.
__global__ __launch_bounds__(256, 2) void main_kernel(
    const float* __restrict__ x, float* __restrict__ ws) {
  const float* centers = ws + W_CENTERS;
  const float* csq  = ws + W_CSQ;
  const float* tpA  = ws + W_TPA;
  const float* tpB  = ws + W_TPB;
  const float* bl   = ws + W_BL;
  const float* Sexp = ws + W_SEXP;
  float* acc8 = ws + W_ACC8;
  double* dS8 = (double*)(ws + W_DS8);

  __shared__ __align__(16) unsigned char smem[49152];
  bf16* xl_h = (bf16*)smem;              // [p][d] row-major, swizzled
  bf16* xl_l = (bf16*)(smem + 8192);
  bf16* xt_h = (bf16*)(smem + 16384);    // [d][p] transposed, swizzled
  bf16* xt_l = (bf16*)(smem + 24576);
  bf16* wt_h = (bf16*)(smem + 32768);    // [c][p] transposed W, swizzled
  bf16* wt_l = (bf16*)(smem + 40960);

  const int tid  = threadIdx.x;
  const int wv   = tid >> 6;
  const int lane = tid & 63;
  const int ln   = lane & 15;
  const int h    = lane >> 4;

  // per-lane time-prior params for the 16 c-rows this lane owns in S^T frags
  float pA_[4][4], pB_[4][4], pC_[4][4], ph_[4][4];
  #pragma unroll
  for (int mc = 0; mc < 4; ++mc)
    #pragma unroll
    for (int r = 0; r < 4; ++r) {
      int c = 16 * mc + 4 * h + r;
      pA_[mc][r] = tpA[c];
      pB_[mc][r] = tpB[c];
      pC_[mc][r] = bl[c] + logf(fmaxf(Sexp[c], EPSF));
      ph_[mc][r] = -0.5f * csq[c];
    }

  // preload C fragments (A-operand of phase 1), hi/lo bf16 split
  bf16x8 cah[4][2], cal[4][2];
  #pragma unroll
  for (int mc = 0; mc < 4; ++mc)
    #pragma unroll
    for (int ks = 0; ks < 2; ++ks) {
      const float* cp = centers + (16 * mc + ln) * 64 + 32 * ks + 8 * h;
      #pragma unroll
      for (int j = 0; j < 8; ++j) {
        float v = cp[j];
        bf16 hh = (bf16)v;
        cah[mc][ks][j] = hh;
        cal[mc][ks][j] = (bf16)(v - (float)hh);
      }
    }

  f32x4 pacc[4];
  #pragma unroll
  for (int tn = 0; tn < 4; ++tn) { pacc[tn].x = 0.f; pacc[tn].y = 0.f; pacc[tn].z = 0.f; pacc[tn].w = 0.f; }
  double ts0 = 0.0, ts1 = 0.0, ts2 = 0.0;

  const int stride = gridDim.x;
  int ch = blockIdx.x;
  f32x4 rv[4];
  {
    const f32x4* xg = (const f32x4*)(x + (size_t)ch * 4096);
    #pragma unroll
    for (int i = 0; i < 4; ++i) rv[i] = xg[tid + 256 * i];
  }

  for (; ch < CHUNKS; ch += stride) {
    const int n0 = ch * 64;
    f32x4 rv2[4];
    const bool hasnext = (ch + stride) < CHUNKS;
    if (hasnext) {
      const f32x4* xg = (const f32x4*)(x + (size_t)(ch + stride) * 4096);
      #pragma unroll
      for (int i = 0; i < 4; ++i) rv2[i] = xg[tid + 256 * i];
    }

    // convert current chunk -> xl (row-major, swizzled)
    #pragma unroll
    for (int i = 0; i < 4; ++i) {
      int p  = (tid >> 4) + 16 * i;
      int d0 = (tid & 15) * 4;
      f32x4 v = rv[i];
      bf16x4 hh, ll;
      #pragma unroll
      for (int j = 0; j < 4; ++j) {
        float vj = (j == 0) ? v.x : (j == 1) ? v.y : (j == 2) ? v.z : v.w;
        bf16 b = (bf16)vj;
        hh[j] = b;
        ll[j] = (bf16)(vj - (float)b);
      }
      int e = p * 64 + (d0 ^ ((p & 7) << 3));
      *(bf16x4*)&xl_h[e] = hh;
      *(bf16x4*)&xl_l[e] = ll;
    }
    __syncthreads();

    // phase 1: S^T[c][p] = C . X^T  (3-term bf16 split), wave wv owns p-slab
    f32x4 facc[4];
    #pragma unroll
    for (int mc = 0; mc < 4; ++mc) {
      facc[mc].x = ph_[mc][0]; facc[mc].y = ph_[mc][1];
      facc[mc].z = ph_[mc][2]; facc[mc].w = ph_[mc][3];
    }
    const int prow = 16 * wv + ln;
    #pragma unroll
    for (int ks = 0; ks < 2; ++ks) {
      int e = prow * 64 + ((32 * ks + 8 * h) ^ ((prow & 7) << 3));
      bf16x8 bxh = *(bf16x8*)&xl_h[e];
      bf16x8 bxl = *(bf16x8*)&xl_l[e];
      #pragma unroll
      for (int mc = 0; mc < 4; ++mc) {
        facc[mc] = mfma16(cah[mc][ks], bxh, facc[mc]);
        facc[mc] = mfma16(cah[mc][ks], bxl, facc[mc]);
        facc[mc] = mfma16(cal[mc][ks], bxh, facc[mc]);
      }
    }

    // epilogue + in-register softmax over c (16 per lane + xor16/xor32)
    {
      float t  = ((float)(n0 + prow) + 0.5f) / (float)NP;
      float lt = logf(t);
      float l1 = log1pf(-t);
      float m = -3.0e38f;
      #pragma unroll
      for (int mc = 0; mc < 4; ++mc)
        #pragma unroll
        for (int r = 0; r < 4; ++r) {
          float u = fmaf(pA_[mc][r], lt, fmaf(pB_[mc][r], l1, -pC_[mc][r]));
          u = fminf(fmaxf(u, -69.0775528f), 0.0f);
          float fa = (r == 0) ? facc[mc].x : (r == 1) ? facc[mc].y : (r == 2) ? facc[mc].z : facc[mc].w;
          float val = fmaf(2.0f, fa, u);
          if (r == 0) facc[mc].x = val; else if (r == 1) facc[mc].y = val;
          else if (r == 2) facc[mc].z = val; else facc[mc].w = val;
          m = fmaxf(m, val);
        }
      m = fmaxf(m, __shfl_xor(m, 16));
      m = fmaxf(m, __shfl_xor(m, 32));
      float lsum = 0.f;
      #pragma unroll
      for (int mc = 0; mc < 4; ++mc) {
        facc[mc].x = __expf(facc[mc].x - m); lsum += facc[mc].x;
        facc[mc].y = __expf(facc[mc].y - m); lsum += facc[mc].y;
        facc[mc].z = __expf(facc[mc].z - m); lsum += facc[mc].z;
        facc[mc].w = __expf(facc[mc].w - m); lsum += facc[mc].w;
      }
      lsum += __shfl_xor(lsum, 16);
      lsum += __shfl_xor(lsum, 32);
      float inv = 1.0f / lsum;
      #pragma unroll
      for (int mc = 0; mc < 4; ++mc)
        #pragma unroll
        for (int r = 0; r < 4; ++r) {
          float wval = ((r == 0) ? facc[mc].x : (r == 1) ? facc[mc].y : (r == 2) ? facc[mc].z : facc[mc].w) * inv;
          bf16 bh = (bf16)wval;
          bf16 bl2 = (bf16)(wval - (float)bh);
          int c = 16 * mc + 4 * h + r;
          int e = c * 64 + (prow ^ ((c & 7) << 3));
          wt_h[e] = bh;
          wt_l[e] = bl2;
        }
    }

    // transpose xl -> xt (row-read / row-write, conflict-free)
    #pragma unroll
    for (int s = 0; s < 2; ++s) {
      int d0 = 8 * (2 * wv + s);
      int ep = lane * 64 + (d0 ^ ((lane & 7) << 3));
      bf16x8 vh = *(bf16x8*)&xl_h[ep];
      bf16x8 vl = *(bf16x8*)&xl_l[ep];
      #pragma unroll
      for (int j = 0; j < 8; ++j) {
        int e = (d0 + j) * 64 + (lane ^ (j << 3));
        xt_h[e] = vh[j];
        xt_l[e] = vl[j];
      }
    }
    __syncthreads();

    // phase 3a: time stats (c = lane, p-slab by wave), fp32 chunk -> fp64
    {
      float c0 = 0.f, c1 = 0.f, c2 = 0.f;
      #pragma unroll
      for (int s = 0; s < 2; ++s) {
        int p0 = 16 * wv + 8 * s;
        int e = lane * 64 + (p0 ^ ((lane & 7) << 3));
        bf16x8 vh = *(bf16x8*)&wt_h[e];
        bf16x8 vl = *(bf16x8*)&wt_l[e];
        #pragma unroll
        for (int j = 0; j < 8; ++j) {
          float wval = (float)vh[j] + (float)vl[j];
          float tt = ((float)(n0 + p0 + j) + 0.5f) / (float)NP;
          c0 += wval;
          c1 = fmaf(wval, tt, c1);
          c2 = fmaf(wval, tt * tt, c2);
        }
      }
      ts0 += (double)c0; ts1 += (double)c1; ts2 += (double)c2;
    }

    // phase 3b: ACC[c][d] += W^T . X  (3-term bf16 split)
    {
      const int ca = 16 * wv + ln;
      #pragma unroll
      for (int ks = 0; ks < 2; ++ks) {
        int p0 = 32 * ks + 8 * h;
        int ea = ca * 64 + (p0 ^ ((ca & 7) << 3));
        bf16x8 awh = *(bf16x8*)&wt_h[ea];
        bf16x8 awl = *(bf16x8*)&wt_l[ea];
        #pragma unroll
        for (int tn = 0; tn < 4; ++tn) {
          int d = 16 * tn + ln;
          int e = d * 64 + (p0 ^ ((d & 7) << 3));
          bf16x8 bxh = *(bf16x8*)&xt_h[e];
          bf16x8 bxl = *(bf16x8*)&xt_l[e];
          pacc[tn] = mfma16(awh, bxh, pacc[tn]);
          pacc[tn] = mfma16(awh, bxl, pacc[tn]);
          pacc[tn] = mfma16(awl, bxh, pacc[tn]);
        }
      }
    }
    __syncthreads();
    if (hasnext) {
      #pragma unroll
      for (int i = 0; i < 4; ++i) rv[i] = rv2[i];
    }
  }

  // flush center numerators into slotted accumulators (64 adds/address)
  const int slot = blockIdx.x & (NSLOT - 1);
  #pragma unroll
  for (int tn = 0; tn < 4; ++tn)
    #pragma unroll
    for (int r = 0; r < 4; ++r) {
      float v = (r == 0) ? pacc[tn].x : (r == 1) ? pacc[tn].y : (r == 2) ? pacc[tn].z : pacc[tn].w;
      unsafeAtomicAdd(&acc8[slot * 4096 + (16 * wv + 4 * h + r) * 64 + 16 * tn + ln], v);
    }

  // block-reduce fp64 stats, then slotted fp64 atomics
  double* dred = (double*)smem;
  dred[tid] = ts0; dred[256 + tid] = ts1; dred[512 + tid] = ts2;
  __syncthreads();
  if (tid < 64) {
    double a0 = (dred[tid] + dred[64 + tid]) + (dred[128 + tid] + dred[192 + tid]);
    double a1 = (dred[256 + tid] + dred[320 + tid]) + (dred[384 + tid] + dred[448 + tid]);
    double a2 = (dred[512 + tid] + dred[576 + tid]) + (dred[640 + tid] + dred[704 + tid]);
    unsafeAtomicAdd(&dS8[slot * 192 + tid], a0);
    unsafeAtomicAdd(&dS8[slot * 192 + 64 + tid], a1);
    unsafeAtomicAdd(&dS8[slot * 192 + 128 + tid], a2);
  }
}

// -------------------------------------------------------------- launch
extern "C" void kernel_launch(void* const* d_in, const int* in_sizes, int n_in,
                              void* d_out, int out_size, void* d_ws, size_t ws_size,
                              hipStream_t stream) {
  const float* x  = (const float*)d_in[0];
  const float* c0 = (const float*)d_in[1];
  float* out = (float*)d_out;
  float* ws  = (float*)d_ws;
  const bool use_tab = ws_size >= (size_t)WS_NEEDED;

  if (use_tab)
    hipLaunchKernelGGL(table_kernel, dim3(1024), dim3(256), 0, stream, ws);

  for (int it = 0; it < 5; ++it) {
    hipLaunchKernelGGL(prep_kernel, dim3(1), dim3(256), 0, stream, c0, ws, out, it);
    if (it > 0) {
      if (use_tab)
        hipLaunchKernelGGL(expsum_tab_kernel, dim3(1024), dim3(256), 0, stream, ws);
      else
        hipLaunchKernelGGL(expsum_kernel, dim3(512), dim3(256), 0, stream, ws);
    }
    hipLaunchKernelGGL(main_kernel, dim3(512), dim3(256), 0, stream, x, ws);
  }
  hipLaunchKernelGGL(prep_kernel, dim3(1), dim3(256), 0, stream, c0, ws, out, 5);
}

// Round 5
// 540.217 us; speedup vs baseline: 2.7293x; 1.7193x over previous
//
#include <hip/hip_runtime.h>

#define NP 400000
#define KC 64
#define DD 64
#define CHUNKS (NP / 64)     // 6250
#define EPSF 1e-10f
#define LOGN 12.8992195f     // log(400000)
#define NSLOT 8

// workspace float-index layout
#define W_CENTERS 0          // 4096
#define W_CSQ   4096         // 64
#define W_TPA   4160
#define W_TPB   4224
#define W_BL    4288
#define W_SEXP  4352
#define W_TM    4416
#define W_TV    4480
#define W_OK    4544
#define W_ACC8  4608         // NSLOT*4096 = 32768 floats
#define W_DS8   37376        // byte off 149504 (8B aligned); NSLOT*192 doubles
#define W_TAB   40448        // byte off 161792; float2[NP] = 3.2 MB
#define WS_NEEDED ((W_TAB + 2 * NP) * 4)

typedef __bf16 bf16;
typedef bf16 bf16x4 __attribute__((ext_vector_type(4)));
typedef bf16 bf16x8 __attribute__((ext_vector_type(8)));
typedef float f32x4 __attribute__((ext_vector_type(4)));

__device__ __forceinline__ f32x4 mfma16(bf16x8 a, bf16x8 b, f32x4 c) {
  return __builtin_amdgcn_mfma_f32_16x16x32_bf16(a, b, c, 0, 0, 0);
}

// ---------------------------------------------------------------- prep
// accumulators (acc8/dS8) are zeroed by hipMemsetAsync in kernel_launch.
__global__ __launch_bounds__(256) void prep_kernel(
    const float* __restrict__ centers0, float* __restrict__ ws,
    float* __restrict__ out, int it) {
  float* centers = ws + W_CENTERS;
  float* csq  = ws + W_CSQ;
  float* tpA  = ws + W_TPA;
  float* tpB  = ws + W_TPB;
  float* bl   = ws + W_BL;
  float* Sexp = ws + W_SEXP;
  float* tm   = ws + W_TM;
  float* tv   = ws + W_TV;
  float* okf  = ws + W_OK;
  float* acc8 = ws + W_ACC8;
  double* dS8 = (double*)(ws + W_DS8);
  const int tid = threadIdx.x;
  __shared__ float sw[64];
  __shared__ float stm[64];
  __shared__ int srank[64];

  if (it == 0) {
    for (int e = tid; e < 4096; e += 256) centers[e] = centers0[e];
    __syncthreads();
    if (tid < 64) {
      float s = 0.f;
      for (int d = 0; d < 64; ++d) { float c = centers[tid * 64 + d]; s = fmaf(c, c, s); }
      csq[tid] = s;
      tpA[tid] = 0.f; tpB[tid] = 0.f; bl[tid] = LOGN; Sexp[tid] = 1.f; okf[tid] = 0.f;
    }
    return;
  }

  // finalize previous iteration: reduce slots
  if (tid < 64) {
    double w = 0.0, s1 = 0.0, s2 = 0.0;
    for (int s = 0; s < NSLOT; ++s) {
      w  += dS8[s * 192 + tid];
      s1 += dS8[s * 192 + 64 + tid];
      s2 += dS8[s * 192 + 128 + tid];
    }
    double md = s1 / (w + 1e-10);
    double vd = (s2 - 2.0 * md * s1 + md * md * w) / (w + 1e-10);
    tm[tid] = (float)md;
    tv[tid] = (float)vd;
    sw[tid] = (float)w;
  }
  __syncthreads();
  for (int e4 = tid; e4 < 1024; e4 += 256) {
    f32x4 s = {0.f, 0.f, 0.f, 0.f};
    #pragma unroll
    for (int slot = 0; slot < NSLOT; ++slot)
      s += *(const f32x4*)&acc8[slot * 4096 + e4 * 4];
    float dv = sw[e4 >> 4] + EPSF;
    s.x /= dv; s.y /= dv; s.z /= dv; s.w /= dv;
    *(f32x4*)&centers[e4 * 4] = s;
  }
  __syncthreads();
  if (tid < 64) {
    float m = tm[tid], var = tv[tid];
    float sigma = sqrtf(fmaxf(var, 0.f));
    bool valid = (sigma > 1e-4f) && (m > 0.f);
    float mu = valid ? m : 0.5f;
    float vvv = valid ? var : 1.f;
    float a = (1.f - mu) * mu * mu / vvv - mu;
    float b = a / mu - a;
    bool ok = valid && (a > 0.f) && (b > 0.f);
    if (ok) {
      bl[tid]  = lgammaf(a) + lgammaf(b) - lgammaf(a + b);
      tpA[tid] = a - 1.f;
      tpB[tid] = b - 1.f;
      okf[tid] = 1.f;
      Sexp[tid] = 0.f;
    } else {
      bl[tid] = LOGN; tpA[tid] = 0.f; tpB[tid] = 0.f; okf[tid] = 0.f; Sexp[tid] = 1.f;
    }
    float s = 0.f;
    for (int d = 0; d < 64; ++d) { float c = centers[tid * 64 + d]; s = fmaf(c, c, s); }
    csq[tid] = s;
  }

  if (it == 5) {  // final: stable argsort by time_means, write output
    __syncthreads();
    if (tid < 64) stm[tid] = tm[tid];
    __syncthreads();
    if (tid < 64) {
      float mk = stm[tid];
      int r = 0;
      for (int j = 0; j < 64; ++j) {
        float mj = stm[j];
        if (mj < mk || (mj == mk && j < tid)) ++r;
      }
      srank[tid] = r;
    }
    __syncthreads();
    for (int e = tid; e < 4096; e += 256)
      out[srank[e >> 6] * 64 + (e & 63)] = centers[e];
  }
}

// --------------------------------------------------- log table (once/call)
__global__ __launch_bounds__(256) void table_kernel(float* __restrict__ ws) {
  float2* tab = (float2*)(ws + W_TAB);
  const int gid = blockIdx.x * 256 + threadIdx.x;
  const int stride = gridDim.x * 256;
  for (int n = gid; n < NP; n += stride) {
    float t = ((float)n + 0.5f) / (float)NP;
    tab[n] = make_float2(logf(t), log1pf(-t));
  }
}

// -------- expsum via table: contiguous slab -> LDS -> broadcast reads.
// 250 blocks x 1600 entries = 400000 exactly.
__global__ __launch_bounds__(256) void expsum_tab_kernel(float* __restrict__ ws) {
  const float* tpA = ws + W_TPA;
  const float* tpB = ws + W_TPB;
  const float* blc = ws + W_BL;
  const float* okf = ws + W_OK;
  const float2* tab = (const float2*)(ws + W_TAB);
  float* Sexp = ws + W_SEXP;
  __shared__ __align__(16) float2 stab[1600];
  __shared__ float sacc[256];
  const int tid  = threadIdx.x;
  const int lane = tid & 63;
  const int wv   = tid >> 6;

  // coalesced stage: this block's contiguous 1600-entry slab (800 float4)
  const f32x4* src = (const f32x4*)(tab + blockIdx.x * 1600);
  f32x4* dst = (f32x4*)stab;
  #pragma unroll
  for (int i = 0; i < 4; ++i) {
    int f = tid + 256 * i;
    if (f < 800) dst[f] = src[f];
  }
  __syncthreads();

  const float A = tpA[lane], B = tpB[lane], C = blc[lane];
  float acc = 0.f;
  const float2* wp = stab + wv * 400;
  #pragma unroll 4
  for (int i = 0; i < 400; ++i) {
    float2 v = wp[i];                       // wave-broadcast LDS read
    acc += __expf(fmaf(A, v.x, fmaf(B, v.y, -C)));
  }
  sacc[tid] = acc;
  __syncthreads();
  if (tid < 64) {
    float tot = (sacc[tid] + sacc[64 + tid]) + (sacc[128 + tid] + sacc[192 + tid]);
    if (okf[tid] > 0.5f) unsafeAtomicAdd(&Sexp[tid], tot);
  }
}

// ---------------------------- expsum fallback (no table space in ws)
__global__ __launch_bounds__(256) void expsum_kernel(float* __restrict__ ws) {
  const float* tpA = ws + W_TPA;
  const float* tpB = ws + W_TPB;
  const float* bl  = ws + W_BL;
  const float* okf = ws + W_OK;
  float* Sexp = ws + W_SEXP;
  const int lane = threadIdx.x & 63;
  const int wid = blockIdx.x * 4 + (threadIdx.x >> 6);
  const int nw = gridDim.x * 4;
  const float A = tpA[lane], B = tpB[lane], C = bl[lane];
  const bool ok = okf[lane] > 0.5f;
  float acc = 0.f;
  for (int n = wid; n < NP; n += nw) {
    float t = ((float)n + 0.5f) / (float)NP;
    float lt = logf(t);
    float l1 = log1pf(-t);
    acc += __expf(fmaf(A, lt, fmaf(B, l1, -C)));
  }
  if (ok) unsafeAtomicAdd(&Sexp[lane], acc);
}

// ---------------------------------------------------------------- main
// Fused MFMA iteration: scores (S^T = C.X^T via bf16-split) -> in-register
// softmax -> W^T.X via bf16-split MFMA + fp64 time stats.
__global__ __launch_bounds__(256, 2) void main_kernel(
    const float* __restrict__ x, float* __restrict__ ws) {
  const float* centers = ws + W_CENTERS;
  const float* csq  = ws + W_CSQ;
  const float* tpA  = ws + W_TPA;
  const float* tpB  = ws + W_TPB;
  const float* bl   = ws + W_BL;
  const float* Sexp = ws + W_SEXP;
  float* acc8 = ws + W_ACC8;
  double* dS8 = (double*)(ws + W_DS8);

  __shared__ __align__(16) unsigned char smem[49152];
  bf16* xl_h = (bf16*)smem;              // [p][d] row-major, swizzled
  bf16* xl_l = (bf16*)(smem + 8192);
  bf16* xt_h = (bf16*)(smem + 16384);    // [d][p] transposed, swizzled
  bf16* xt_l = (bf16*)(smem + 24576);
  bf16* wt_h = (bf16*)(smem + 32768);    // [c][p] transposed W, swizzled
  bf16* wt_l = (bf16*)(smem + 40960);

  const int tid  = threadIdx.x;
  const int wv   = tid >> 6;
  const int lane = tid & 63;
  const int ln   = lane & 15;
  const int h    = lane >> 4;

  // per-lane time-prior params for the 16 c-rows this lane owns in S^T frags
  float pA_[4][4], pB_[4][4], pC_[4][4], ph_[4][4];
  #pragma unroll
  for (int mc = 0; mc < 4; ++mc)
    #pragma unroll
    for (int r = 0; r < 4; ++r) {
      int c = 16 * mc + 4 * h + r;
      pA_[mc][r] = tpA[c];
      pB_[mc][r] = tpB[c];
      pC_[mc][r] = bl[c] + logf(fmaxf(Sexp[c], EPSF));
      ph_[mc][r] = -0.5f * csq[c];
    }

  // preload C fragments (A-operand of phase 1), hi/lo bf16 split
  bf16x8 cah[4][2], cal[4][2];
  #pragma unroll
  for (int mc = 0; mc < 4; ++mc)
    #pragma unroll
    for (int ks = 0; ks < 2; ++ks) {
      const float* cp = centers + (16 * mc + ln) * 64 + 32 * ks + 8 * h;
      #pragma unroll
      for (int j = 0; j < 8; ++j) {
        float v = cp[j];
        bf16 hh = (bf16)v;
        cah[mc][ks][j] = hh;
        cal[mc][ks][j] = (bf16)(v - (float)hh);
      }
    }

  f32x4 pacc[4];
  #pragma unroll
  for (int tn = 0; tn < 4; ++tn) { pacc[tn].x = 0.f; pacc[tn].y = 0.f; pacc[tn].z = 0.f; pacc[tn].w = 0.f; }
  double ts0 = 0.0, ts1 = 0.0, ts2 = 0.0;

  const int stride = gridDim.x;
  int ch = blockIdx.x;
  f32x4 rv[4];
  {
    const f32x4* xg = (const f32x4*)(x + (size_t)ch * 4096);
    #pragma unroll
    for (int i = 0; i < 4; ++i) rv[i] = xg[tid + 256 * i];
  }

  for (; ch < CHUNKS; ch += stride) {
    const int n0 = ch * 64;
    f32x4 rv2[4];
    const bool hasnext = (ch + stride) < CHUNKS;
    if (hasnext) {
      const f32x4* xg = (const f32x4*)(x + (size_t)(ch + stride) * 4096);
      #pragma unroll
      for (int i = 0; i < 4; ++i) rv2[i] = xg[tid + 256 * i];
    }

    // convert current chunk -> xl (row-major, swizzled)
    #pragma unroll
    for (int i = 0; i < 4; ++i) {
      int p  = (tid >> 4) + 16 * i;
      int d0 = (tid & 15) * 4;
      f32x4 v = rv[i];
      bf16x4 hh, ll;
      #pragma unroll
      for (int j = 0; j < 4; ++j) {
        float vj = (j == 0) ? v.x : (j == 1) ? v.y : (j == 2) ? v.z : v.w;
        bf16 b = (bf16)vj;
        hh[j] = b;
        ll[j] = (bf16)(vj - (float)b);
      }
      int e = p * 64 + (d0 ^ ((p & 7) << 3));
      *(bf16x4*)&xl_h[e] = hh;
      *(bf16x4*)&xl_l[e] = ll;
    }
    __syncthreads();

    // phase 1: S^T[c][p] = C . X^T  (3-term bf16 split), wave wv owns p-slab
    f32x4 facc[4];
    #pragma unroll
    for (int mc = 0; mc < 4; ++mc) {
      facc[mc].x = ph_[mc][0]; facc[mc].y = ph_[mc][1];
      facc[mc].z = ph_[mc][2]; facc[mc].w = ph_[mc][3];
    }
    const int prow = 16 * wv + ln;
    #pragma unroll
    for (int ks = 0; ks < 2; ++ks) {
      int e = prow * 64 + ((32 * ks + 8 * h) ^ ((prow & 7) << 3));
      bf16x8 bxh = *(bf16x8*)&xl_h[e];
      bf16x8 bxl = *(bf16x8*)&xl_l[e];
      #pragma unroll
      for (int mc = 0; mc < 4; ++mc) {
        facc[mc] = mfma16(cah[mc][ks], bxh, facc[mc]);
        facc[mc] = mfma16(cah[mc][ks], bxl, facc[mc]);
        facc[mc] = mfma16(cal[mc][ks], bxh, facc[mc]);
      }
    }

    // epilogue + in-register softmax over c (16 per lane + xor16/xor32)
    {
      float t  = ((float)(n0 + prow) + 0.5f) / (float)NP;
      float lt = logf(t);
      float l1 = log1pf(-t);
      float m = -3.0e38f;
      #pragma unroll
      for (int mc = 0; mc < 4; ++mc)
        #pragma unroll
        for (int r = 0; r < 4; ++r) {
          float u = fmaf(pA_[mc][r], lt, fmaf(pB_[mc][r], l1, -pC_[mc][r]));
          u = fminf(fmaxf(u, -69.0775528f), 0.0f);
          float fa = (r == 0) ? facc[mc].x : (r == 1) ? facc[mc].y : (r == 2) ? facc[mc].z : facc[mc].w;
          float val = fmaf(2.0f, fa, u);
          if (r == 0) facc[mc].x = val; else if (r == 1) facc[mc].y = val;
          else if (r == 2) facc[mc].z = val; else facc[mc].w = val;
          m = fmaxf(m, val);
        }
      m = fmaxf(m, __shfl_xor(m, 16));
      m = fmaxf(m, __shfl_xor(m, 32));
      float lsum = 0.f;
      #pragma unroll
      for (int mc = 0; mc < 4; ++mc) {
        facc[mc].x = __expf(facc[mc].x - m); lsum += facc[mc].x;
        facc[mc].y = __expf(facc[mc].y - m); lsum += facc[mc].y;
        facc[mc].z = __expf(facc[mc].z - m); lsum += facc[mc].z;
        facc[mc].w = __expf(facc[mc].w - m); lsum += facc[mc].w;
      }
      lsum += __shfl_xor(lsum, 16);
      lsum += __shfl_xor(lsum, 32);
      float inv = 1.0f / lsum;
      #pragma unroll
      for (int mc = 0; mc < 4; ++mc)
        #pragma unroll
        for (int r = 0; r < 4; ++r) {
          float wval = ((r == 0) ? facc[mc].x : (r == 1) ? facc[mc].y : (r == 2) ? facc[mc].z : facc[mc].w) * inv;
          bf16 bh = (bf16)wval;
          bf16 bl2 = (bf16)(wval - (float)bh);
          int c = 16 * mc + 4 * h + r;
          int e = c * 64 + (prow ^ ((c & 7) << 3));
          wt_h[e] = bh;
          wt_l[e] = bl2;
        }
    }

    // transpose xl -> xt (row-read / row-write, conflict-free)
    #pragma unroll
    for (int s = 0; s < 2; ++s) {
      int d0 = 8 * (2 * wv + s);
      int ep = lane * 64 + (d0 ^ ((lane & 7) << 3));
      bf16x8 vh = *(bf16x8*)&xl_h[ep];
      bf16x8 vl = *(bf16x8*)&xl_l[ep];
      #pragma unroll
      for (int j = 0; j < 8; ++j) {
        int e = (d0 + j) * 64 + (lane ^ (j << 3));
        xt_h[e] = vh[j];
        xt_l[e] = vl[j];
      }
    }
    __syncthreads();

    // phase 3a: time stats (c = lane, p-slab by wave), fp32 chunk -> fp64
    {
      float c0 = 0.f, c1 = 0.f, c2 = 0.f;
      #pragma unroll
      for (int s = 0; s < 2; ++s) {
        int p0 = 16 * wv + 8 * s;
        int e = lane * 64 + (p0 ^ ((lane & 7) << 3));
        bf16x8 vh = *(bf16x8*)&wt_h[e];
        bf16x8 vl = *(bf16x8*)&wt_l[e];
        #pragma unroll
        for (int j = 0; j < 8; ++j) {
          float wval = (float)vh[j] + (float)vl[j];
          float tt = ((float)(n0 + p0 + j) + 0.5f) / (float)NP;
          c0 += wval;
          c1 = fmaf(wval, tt, c1);
          c2 = fmaf(wval, tt * tt, c2);
        }
      }
      ts0 += (double)c0; ts1 += (double)c1; ts2 += (double)c2;
    }

    // phase 3b: ACC[c][d] += W^T . X  (3-term bf16 split)
    {
      const int ca = 16 * wv + ln;
      #pragma unroll
      for (int ks = 0; ks < 2; ++ks) {
        int p0 = 32 * ks + 8 * h;
        int ea = ca * 64 + (p0 ^ ((ca & 7) << 3));
        bf16x8 awh = *(bf16x8*)&wt_h[ea];
        bf16x8 awl = *(bf16x8*)&wt_l[ea];
        #pragma unroll
        for (int tn = 0; tn < 4; ++tn) {
          int d = 16 * tn + ln;
          int e = d * 64 + (p0 ^ ((d & 7) << 3));
          bf16x8 bxh = *(bf16x8*)&xt_h[e];
          bf16x8 bxl = *(bf16x8*)&xt_l[e];
          pacc[tn] = mfma16(awh, bxh, pacc[tn]);
          pacc[tn] = mfma16(awh, bxl, pacc[tn]);
          pacc[tn] = mfma16(awl, bxh, pacc[tn]);
        }
      }
    }
    __syncthreads();
    if (hasnext) {
      #pragma unroll
      for (int i = 0; i < 4; ++i) rv[i] = rv2[i];
    }
  }

  // flush center numerators into slotted accumulators (64 adds/address)
  const int slot = blockIdx.x & (NSLOT - 1);
  #pragma unroll
  for (int tn = 0; tn < 4; ++tn)
    #pragma unroll
    for (int r = 0; r < 4; ++r) {
      float v = (r == 0) ? pacc[tn].x : (r == 1) ? pacc[tn].y : (r == 2) ? pacc[tn].z : pacc[tn].w;
      unsafeAtomicAdd(&acc8[slot * 4096 + (16 * wv + 4 * h + r) * 64 + 16 * tn + ln], v);
    }

  // block-reduce fp64 stats, then slotted fp64 atomics
  double* dred = (double*)smem;
  dred[tid] = ts0; dred[256 + tid] = ts1; dred[512 + tid] = ts2;
  __syncthreads();
  if (tid < 64) {
    double a0 = (dred[tid] + dred[64 + tid]) + (dred[128 + tid] + dred[192 + tid]);
    double a1 = (dred[256 + tid] + dred[320 + tid]) + (dred[384 + tid] + dred[448 + tid]);
    double a2 = (dred[512 + tid] + dred[576 + tid]) + (dred[640 + tid] + dred[704 + tid]);
    unsafeAtomicAdd(&dS8[slot * 192 + tid], a0);
    unsafeAtomicAdd(&dS8[slot * 192 + 64 + tid], a1);
    unsafeAtomicAdd(&dS8[slot * 192 + 128 + tid], a2);
  }
}

// -------------------------------------------------------------- launch
extern "C" void kernel_launch(void* const* d_in, const int* in_sizes, int n_in,
                              void* d_out, int out_size, void* d_ws, size_t ws_size,
                              hipStream_t stream) {
  const float* x  = (const float*)d_in[0];
  const float* c0 = (const float*)d_in[1];
  float* out = (float*)d_out;
  float* ws  = (float*)d_ws;
  const bool use_tab = ws_size >= (size_t)WS_NEEDED;

  if (use_tab)
    hipLaunchKernelGGL(table_kernel, dim3(1024), dim3(256), 0, stream, ws);

  for (int it = 0; it < 5; ++it) {
    hipLaunchKernelGGL(prep_kernel, dim3(1), dim3(256), 0, stream, c0, ws, out, it);
    // zero acc8 + dS8 (contiguous: byte 18432 .. 161792)
    hipMemsetAsync((char*)d_ws + W_ACC8 * 4, 0, (W_TAB - W_ACC8) * 4, stream);
    if (it > 0) {
      if (use_tab)
        hipLaunchKernelGGL(expsum_tab_kernel, dim3(250), dim3(256), 0, stream, ws);
      else
        hipLaunchKernelGGL(expsum_kernel, dim3(512), dim3(256), 0, stream, ws);
    }
    hipLaunchKernelGGL(main_kernel, dim3(512), dim3(256), 0, stream, x, ws);
  }
  hipLaunchKernelGGL(prep_kernel, dim3(1), dim3(256), 0, stream, c0, ws, out, 5);
}